// Round 12
// baseline (114.724 us; speedup 1.0000x reference)
//
#include <hip/hip_runtime.h>

// Problem constants (fixed by the reference setup):
// B=16, C=64, NC=12500, N=50000, K=8, E=NC*K=100000
#define NCLIQ  12500
#define NODES  50000
#define NEDGE  100000
#define NGRP   64                                  // 1024 bc / 16 per group
#define ELLW   16                                  // slots/node (dataset max deg <= 16, validated R5+)

#define FILL_BLOCKS   ((NEDGE + 255) / 256)        // 391
#define COL4          (NCLIQ / 4)                  // 3125 (NCLIQ % 4 == 0)
#define PACK_BLOCKS_X ((COL4 + 255) / 256)         // 13
#define PACK_BLOCKS   (PACK_BLOCKS_X * NGRP)       // 832

#define NODEB 256                                  // nodes per gather block (4 x 64-node passes)
#define NBLK  ((NODES + NODEB - 1) / NODEB)        // 196

typedef float    f32x4 __attribute__((ext_vector_type(4)));
typedef unsigned u32x4 __attribute__((ext_vector_type(4)));

// ---------------- zero degree counters ----------------

__global__ __launch_bounds__(256) void zero_counts(int4* __restrict__ counts4) {
    int t = blockIdx.x * 256 + threadIdx.x;
    if (t < NODES / 4) counts4[t] = make_int4(0, 0, 0, 0);
}

// ---------------- fused: ushort-ELL build + 16-bc input pack ----------------
// blocks [0, FILL_BLOCKS): pos = atomic cursor per node; ell16[n][pos] = clique.
// blocks [FILL_BLOCKS, ..): in[bc][col] -> inP[g][col][j], j = bc%16 (64B line/col).

__global__ __launch_bounds__(256) void fill_pack(const int* __restrict__ node_ids,
                                                 const int* __restrict__ clique_ids,
                                                 int* __restrict__ counts,
                                                 unsigned short* __restrict__ ell16,
                                                 const float* __restrict__ in,
                                                 float* __restrict__ inP) {
    int b   = blockIdx.x;
    int tid = threadIdx.x;
    if (b < FILL_BLOCKS) {
        int e = b * 256 + tid;
        if (e < NEDGE) {
            int n   = node_ids[e];
            int pos = atomicAdd(&counts[n], 1);
            if (pos < ELLW) ell16[(size_t)n * ELLW + pos] = (unsigned short)clique_ids[e];
        }
    } else {
        int pb = b - FILL_BLOCKS;
        int g  = pb / PACK_BLOCKS_X;
        int c4 = (pb % PACK_BLOCKS_X) * 256 + tid;
        if (c4 < COL4) {
            f32x4 v[16];                           // v[j][ci] = in[g*16+j][4*c4+ci]
            #pragma unroll
            for (int j = 0; j < 16; ++j)
                v[j] = *reinterpret_cast<const f32x4*>(
                    in + (size_t)(g * 16 + j) * NCLIQ + 4 * c4);
            #pragma unroll
            for (int ci = 0; ci < 4; ++ci) {
                f32x4* line = reinterpret_cast<f32x4*>(
                    inP + ((size_t)g * NCLIQ + 4 * c4 + ci) * 16);
                #pragma unroll
                for (int q = 0; q < 4; ++q) {
                    f32x4 t = { v[4 * q + 0][ci], v[4 * q + 1][ci],
                                v[4 * q + 2][ci], v[4 * q + 3][ci] };
                    line[q] = t;
                }
            }
        }
    }
}

// ---------------- gather: R8 pairing, 256-node blocks, 1KB-run stores ----------------
// Block = (gA, gB = gA+8) x 256 nodes. 4 unrolled compute passes (64 nodes
// each, R8's exact per-pass body); passes are independent -> 4x outstanding
// gather loads. One barrier. Store phase writes each plane as a 1KB contiguous
// run (4 consecutive 256B f32x4 NT instructions) — full HBM-row-sized runs,
// attacking the ~2.4 TB/s scattered-segment write ceiling seen in R5/R6.
// Concurrent random-access set per XCD: 2 inP slices (1.6MB) + ell16/deg
// (1.8MB) < 4MB L2 (R10 lesson: never more than 2 slices).
// LDS [2][256][17] = 34.8KB -> 4 blocks/CU (16 waves, enough for BW-bound).
// Both LDS phases exactly 2-way bank-aliased at pad 17 (= free, m136).

__global__ __launch_bounds__(256) void gather_ell(const float* __restrict__ inP,
                                                  const int* __restrict__ deg,
                                                  const unsigned short* __restrict__ ell16,
                                                  float* __restrict__ out) {
    __shared__ float lds[2][NODEB][17];
    int b   = blockIdx.x;                       // [0, (NGRP/2)*NBLK)
    int k   = b & 7;                            // XCD slot
    int r   = b >> 3;
    int nb  = r % NBLK;
    int pp  = r / NBLK;                         // pair-phase 0..3
    int gA  = pp * 16 + k;
    int gB  = gA + 8;
    int tid = threadIdx.x;
    int s   = tid >> 2;                         // node-local 0..63 within pass
    int q   = tid & 3;                          // plane quad 0..3

    const float* __restrict__ baseA = inP + (size_t)gA * NCLIQ * 16 + q * 4;
    const float* __restrict__ baseB = inP + (size_t)gB * NCLIQ * 16 + q * 4;

    #pragma unroll
    for (int c = 0; c < 4; ++c) {
        int n = nb * NODEB + c * 64 + s;
        float4 aA = make_float4(0.f, 0.f, 0.f, 0.f);
        float4 aB = make_float4(0.f, 0.f, 0.f, 0.f);
        if (n < NODES) {
            int d = deg[n];
            const u32x4 e = *reinterpret_cast<const u32x4*>(ell16 + (size_t)n * ELLW);
            unsigned cs[8] = { e.x & 0xFFFFu, e.x >> 16, e.y & 0xFFFFu, e.y >> 16,
                               e.z & 0xFFFFu, e.z >> 16, e.w & 0xFFFFu, e.w >> 16 };
            #pragma unroll
            for (int i = 0; i < 8; ++i) {
                if (i < d) {
                    size_t off = (size_t)cs[i] * 16;
                    const float4 pA = *reinterpret_cast<const float4*>(baseA + off);
                    const float4 pB = *reinterpret_cast<const float4*>(baseB + off);
                    aA.x += pA.x; aA.y += pA.y; aA.z += pA.z; aA.w += pA.w;
                    aB.x += pB.x; aB.y += pB.y; aB.z += pB.z; aB.w += pB.w;
                }
            }
            if (d > 8) {                        // P(deg>8) ~ 0.1%: scalar tail
                for (int i = 8; i < d && i < ELLW; ++i) {
                    size_t off = (size_t)ell16[(size_t)n * ELLW + i] * 16;
                    const float4 pA = *reinterpret_cast<const float4*>(baseA + off);
                    const float4 pB = *reinterpret_cast<const float4*>(baseB + off);
                    aA.x += pA.x; aA.y += pA.y; aA.z += pA.z; aA.w += pA.w;
                    aB.x += pB.x; aB.y += pB.y; aB.z += pB.z; aB.w += pB.w;
                }
            }
        }
        int sl = c * 64 + s;
        lds[0][sl][q * 4 + 0] = aA.x;  lds[0][sl][q * 4 + 1] = aA.y;
        lds[0][sl][q * 4 + 2] = aA.z;  lds[0][sl][q * 4 + 3] = aA.w;
        lds[1][sl][q * 4 + 0] = aB.x;  lds[1][sl][q * 4 + 1] = aB.y;
        lds[1][sl][q * 4 + 2] = aB.z;  lds[1][sl][q * 4 + 3] = aB.w;
    }
    __syncthreads();

    int p  = tid >> 4;                          // plane 0..15
    int i4 = (tid & 15) * 4;                    // node chunk within 64-node slab
    #pragma unroll
    for (int c = 0; c < 4; ++c) {
        int sl = c * 64 + i4;
        int n0 = nb * NODEB + sl;
        if (n0 + 3 < NODES) {                   // NODES%4==0: no partial vec4
            f32x4 oA = { lds[0][sl][p],     lds[0][sl + 1][p],
                         lds[0][sl + 2][p], lds[0][sl + 3][p] };
            f32x4 oB = { lds[1][sl][p],     lds[1][sl + 1][p],
                         lds[1][sl + 2][p], lds[1][sl + 3][p] };
            __builtin_nontemporal_store(oA,
                reinterpret_cast<f32x4*>(out + (size_t)(gA * 16 + p) * NODES + n0));
            __builtin_nontemporal_store(oB,
                reinterpret_cast<f32x4*>(out + (size_t)(gB * 16 + p) * NODES + n0));
        }
    }
}

// ---------------- launch ----------------

extern "C" void kernel_launch(void* const* d_in, const int* in_sizes, int n_in,
                              void* d_out, int out_size, void* d_ws, size_t ws_size,
                              hipStream_t stream) {
    const float* in         = (const float*)d_in[0];
    const int*   node_ids   = (const int*)d_in[1];
    const int*   clique_ids = (const int*)d_in[2];
    float*       out        = (float*)d_out;

    // ws layout: counts[50000] int | ell16[50000*16] ushort | inP[64*12500*16] float
    int*            counts = (int*)d_ws;
    unsigned short* ell16  = (unsigned short*)(counts + NODES);          // byte 200,000
    float*          inP    = (float*)((char*)d_ws + 200000 + 1600000);   // byte 1,800,000 (16B-aligned)

    zero_counts<<<(NODES / 4 + 255) / 256, 256, 0, stream>>>((int4*)counts);
    fill_pack<<<FILL_BLOCKS + PACK_BLOCKS, 256, 0, stream>>>(node_ids, clique_ids,
                                                             counts, ell16, in, inP);
    gather_ell<<<(NGRP / 2) * NBLK, 256, 0, stream>>>(inP, counts, ell16, out);
}

// Round 13
// 102.904 us; speedup vs baseline: 1.1149x; 1.1149x over previous
//
#include <hip/hip_runtime.h>

// Problem constants (fixed by the reference setup):
// B=16, C=64, NC=12500, N=50000, K=8, E=NC*K=100000
#define NCLIQ  12500
#define NODES  50000
#define NEDGE  100000
#define NGRP   64                                  // 1024 bc / 16 per group
#define ELLW   16                                  // slots/node (dataset max deg <= 16, validated R5+)

#define FILL_BLOCKS   ((NEDGE + 255) / 256)        // 391
#define COL4          (NCLIQ / 4)                  // 3125 (NCLIQ % 4 == 0)
#define PACK_BLOCKS_X ((COL4 + 255) / 256)         // 13
#define PACK_BLOCKS   (PACK_BLOCKS_X * NGRP)       // 832

#define NODEB 64                                   // nodes per gather block
#define NBLK  ((NODES + NODEB - 1) / NODEB)        // 782

typedef float    f32x4 __attribute__((ext_vector_type(4)));
typedef unsigned u32x4 __attribute__((ext_vector_type(4)));

// ---------------- zero degree counters ----------------

__global__ __launch_bounds__(256) void zero_counts(int4* __restrict__ counts4) {
    int t = blockIdx.x * 256 + threadIdx.x;
    if (t < NODES / 4) counts4[t] = make_int4(0, 0, 0, 0);
}

// ---------------- fused: ushort-ELL build + 16-bc input pack ----------------
// blocks [0, FILL_BLOCKS): pos = atomic cursor per node; ell16[n][pos] = clique.
// blocks [FILL_BLOCKS, ..): in[bc][col] -> inP[g][col][j], j = bc%16 (64B line/col).

__global__ __launch_bounds__(256) void fill_pack(const int* __restrict__ node_ids,
                                                 const int* __restrict__ clique_ids,
                                                 int* __restrict__ counts,
                                                 unsigned short* __restrict__ ell16,
                                                 const float* __restrict__ in,
                                                 float* __restrict__ inP) {
    int b   = blockIdx.x;
    int tid = threadIdx.x;
    if (b < FILL_BLOCKS) {
        int e = b * 256 + tid;
        if (e < NEDGE) {
            int n   = node_ids[e];
            int pos = atomicAdd(&counts[n], 1);
            if (pos < ELLW) ell16[(size_t)n * ELLW + pos] = (unsigned short)clique_ids[e];
        }
    } else {
        int pb = b - FILL_BLOCKS;
        int g  = pb / PACK_BLOCKS_X;
        int c4 = (pb % PACK_BLOCKS_X) * 256 + tid;
        if (c4 < COL4) {
            f32x4 v[16];                           // v[j][ci] = in[g*16+j][4*c4+ci]
            #pragma unroll
            for (int j = 0; j < 16; ++j)
                v[j] = *reinterpret_cast<const f32x4*>(
                    in + (size_t)(g * 16 + j) * NCLIQ + 4 * c4);
            #pragma unroll
            for (int ci = 0; ci < 4; ++ci) {
                f32x4* line = reinterpret_cast<f32x4*>(
                    inP + ((size_t)g * NCLIQ + 4 * c4 + ci) * 16);
                #pragma unroll
                for (int q = 0; q < 4; ++q) {
                    f32x4 t = { v[4 * q + 0][ci], v[4 * q + 1][ci],
                                v[4 * q + 2][ci], v[4 * q + 3][ci] };
                    line[q] = t;
                }
            }
        }
    }
}

// ---------------- gather: R8 structure verbatim, SINGLE CHANGE: plain stores ----------
// 2 groups per block (gA, gB = gA+8 share one XCD phase): ELL uint4 + deg +
// 8 bfe decodes + addressing paid once for both groups; 2 groups' inP loads
// independent -> up to 16 outstanding per thread. Per-XCD working set: 2 inP
// slices (1.6MB) + ell16 (1.6MB) + deg (0.2MB) = 3.4MB < 4MB L2.
// Store: acc -> LDS [2][64][17], one barrier, then 2 PLAIN f32x4 stores per
// thread (A/B vs R8's NT: hypothesis = L2 write-combining drains 205MB at
// fill-kernel rate ~7TB/s instead of NT's ~3.6TB/s scattered-segment path).

__global__ __launch_bounds__(256) void gather_ell(const float* __restrict__ inP,
                                                  const int* __restrict__ deg,
                                                  const unsigned short* __restrict__ ell16,
                                                  float* __restrict__ out) {
    __shared__ float lds[2][NODEB][17];
    int b     = blockIdx.x;                     // [0, (NGRP/2)*NBLK)
    int k     = b & 7;                          // XCD slot
    int r     = b >> 3;
    int nb    = r % NBLK;
    int pp    = r / NBLK;                       // pair-phase 0..3
    int gA    = pp * 16 + k;
    int gB    = gA + 8;
    int tid   = threadIdx.x;
    int s     = tid >> 2;                       // node-local 0..63
    int q     = tid & 3;                        // plane quad 0..3
    int n     = nb * NODEB + s;

    float4 aA = make_float4(0.f, 0.f, 0.f, 0.f);
    float4 aB = make_float4(0.f, 0.f, 0.f, 0.f);
    if (n < NODES) {
        int d = deg[n];
        const u32x4 e = *reinterpret_cast<const u32x4*>(ell16 + (size_t)n * ELLW);
        unsigned cs[8] = { e.x & 0xFFFFu, e.x >> 16, e.y & 0xFFFFu, e.y >> 16,
                           e.z & 0xFFFFu, e.z >> 16, e.w & 0xFFFFu, e.w >> 16 };
        const float* __restrict__ baseA = inP + (size_t)gA * NCLIQ * 16 + q * 4;
        const float* __restrict__ baseB = inP + (size_t)gB * NCLIQ * 16 + q * 4;
        #pragma unroll
        for (int i = 0; i < 8; ++i) {
            if (i < d) {
                size_t off = (size_t)cs[i] * 16;
                const float4 pA = *reinterpret_cast<const float4*>(baseA + off);
                const float4 pB = *reinterpret_cast<const float4*>(baseB + off);
                aA.x += pA.x; aA.y += pA.y; aA.z += pA.z; aA.w += pA.w;
                aB.x += pB.x; aB.y += pB.y; aB.z += pB.z; aB.w += pB.w;
            }
        }
        if (d > 8) {                            // P(deg>8) ~ 0.1%: scalar tail
            for (int i = 8; i < d && i < ELLW; ++i) {
                size_t off = (size_t)ell16[(size_t)n * ELLW + i] * 16;
                const float4 pA = *reinterpret_cast<const float4*>(baseA + off);
                const float4 pB = *reinterpret_cast<const float4*>(baseB + off);
                aA.x += pA.x; aA.y += pA.y; aA.z += pA.z; aA.w += pA.w;
                aB.x += pB.x; aB.y += pB.y; aB.z += pB.z; aB.w += pB.w;
            }
        }
    }
    lds[0][s][q * 4 + 0] = aA.x;  lds[0][s][q * 4 + 1] = aA.y;
    lds[0][s][q * 4 + 2] = aA.z;  lds[0][s][q * 4 + 3] = aA.w;
    lds[1][s][q * 4 + 0] = aB.x;  lds[1][s][q * 4 + 1] = aB.y;
    lds[1][s][q * 4 + 2] = aB.z;  lds[1][s][q * 4 + 3] = aB.w;
    __syncthreads();

    int p  = tid >> 4;                          // plane 0..15
    int i4 = (tid & 15) * 4;                    // node chunk base
    int n0 = nb * NODEB + i4;
    if (n0 + 3 < NODES) {                       // NODES%4==0: no partial vec4
        f32x4 oA = { lds[0][i4][p], lds[0][i4 + 1][p], lds[0][i4 + 2][p], lds[0][i4 + 3][p] };
        f32x4 oB = { lds[1][i4][p], lds[1][i4 + 1][p], lds[1][i4 + 2][p], lds[1][i4 + 3][p] };
        *reinterpret_cast<f32x4*>(out + (size_t)(gA * 16 + p) * NODES + n0) = oA;
        *reinterpret_cast<f32x4*>(out + (size_t)(gB * 16 + p) * NODES + n0) = oB;
    }
}

// ---------------- launch ----------------

extern "C" void kernel_launch(void* const* d_in, const int* in_sizes, int n_in,
                              void* d_out, int out_size, void* d_ws, size_t ws_size,
                              hipStream_t stream) {
    const float* in         = (const float*)d_in[0];
    const int*   node_ids   = (const int*)d_in[1];
    const int*   clique_ids = (const int*)d_in[2];
    float*       out        = (float*)d_out;

    // ws layout: counts[50000] int | ell16[50000*16] ushort | inP[64*12500*16] float
    int*            counts = (int*)d_ws;
    unsigned short* ell16  = (unsigned short*)(counts + NODES);          // byte 200,000
    float*          inP    = (float*)((char*)d_ws + 200000 + 1600000);   // byte 1,800,000 (16B-aligned)

    zero_counts<<<(NODES / 4 + 255) / 256, 256, 0, stream>>>((int4*)counts);
    fill_pack<<<FILL_BLOCKS + PACK_BLOCKS, 256, 0, stream>>>(node_ids, clique_ids,
                                                             counts, ell16, in, inP);
    gather_ell<<<(NGRP / 2) * NBLK, 256, 0, stream>>>(inP, counts, ell16, out);
}

// Round 14
// 94.121 us; speedup vs baseline: 1.2189x; 1.0933x over previous
//
#include <hip/hip_runtime.h>

// Problem constants (fixed by the reference setup):
// B=16, C=64, NC=12500, N=50000, K=8, E=NC*K=100000
#define NCLIQ  12500
#define NODES  50000
#define NEDGE  100000
#define NGRP   64                                  // 1024 bc / 16 per group
#define ELLW   16                                  // slots/node (dataset max deg <= 16, validated R5+)

#define FILL_BLOCKS   ((NEDGE + 255) / 256)        // 391
#define COL4          (NCLIQ / 4)                  // 3125 (NCLIQ % 4 == 0)
#define PACK_BLOCKS_X ((COL4 + 255) / 256)         // 13
#define PACK_BLOCKS   (PACK_BLOCKS_X * NGRP)       // 832

#define NODEB 64                                   // nodes per gather block
#define NBLK  ((NODES + NODEB - 1) / NODEB)        // 782

typedef float    f32x4 __attribute__((ext_vector_type(4)));
typedef unsigned u32x4 __attribute__((ext_vector_type(4)));

// ---------------- zero degree counters ----------------

__global__ __launch_bounds__(256) void zero_counts(int4* __restrict__ counts4) {
    int t = blockIdx.x * 256 + threadIdx.x;
    if (t < NODES / 4) counts4[t] = make_int4(0, 0, 0, 0);
}

// ---------------- fused: ushort-ELL build + 16-bc input pack ----------------
// blocks [0, FILL_BLOCKS): pos = atomic cursor per node; ell16[n][pos] = clique.
// blocks [FILL_BLOCKS, ..): in[bc][col] -> inP[g][col][j], j = bc%16 (64B line/col).

__global__ __launch_bounds__(256) void fill_pack(const int* __restrict__ node_ids,
                                                 const int* __restrict__ clique_ids,
                                                 int* __restrict__ counts,
                                                 unsigned short* __restrict__ ell16,
                                                 const float* __restrict__ in,
                                                 float* __restrict__ inP) {
    int b   = blockIdx.x;
    int tid = threadIdx.x;
    if (b < FILL_BLOCKS) {
        int e = b * 256 + tid;
        if (e < NEDGE) {
            int n   = node_ids[e];
            int pos = atomicAdd(&counts[n], 1);
            if (pos < ELLW) ell16[(size_t)n * ELLW + pos] = (unsigned short)clique_ids[e];
        }
    } else {
        int pb = b - FILL_BLOCKS;
        int g  = pb / PACK_BLOCKS_X;
        int c4 = (pb % PACK_BLOCKS_X) * 256 + tid;
        if (c4 < COL4) {
            f32x4 v[16];                           // v[j][ci] = in[g*16+j][4*c4+ci]
            #pragma unroll
            for (int j = 0; j < 16; ++j)
                v[j] = *reinterpret_cast<const f32x4*>(
                    in + (size_t)(g * 16 + j) * NCLIQ + 4 * c4);
            #pragma unroll
            for (int ci = 0; ci < 4; ++ci) {
                f32x4* line = reinterpret_cast<f32x4*>(
                    inP + ((size_t)g * NCLIQ + 4 * c4 + ci) * 16);
                #pragma unroll
                for (int q = 0; q < 4; ++q) {
                    f32x4 t = { v[4 * q + 0][ci], v[4 * q + 1][ci],
                                v[4 * q + 2][ci], v[4 * q + 3][ci] };
                    line[q] = t;
                }
            }
        }
    }
}

// ---------------- gather: R8 verified optimum (locked) ----------------
// 2 groups per block (gA, gB = gA+8 share one XCD phase): ELL uint4 + deg +
// 8 bfe decodes + addressing paid once for both groups; the 2 groups' inP
// loads are independent -> up to 16 outstanding per thread. Per-XCD working
// set: 2 inP slices (1.6MB) + ell16 (1.6MB) + deg (0.2MB) = 3.4MB < 4MB L2.
// A/B ledger: 4 slices (R10) thrashes L2; in-block phase loop (R11) serializes;
// 1KB-run stores (R12) lose occupancy; plain stores (R13) +8.6us (L2 write-
// allocate double-handles 205MB and evicts slices). NT 256B-segment stores
// (~3.5TB/s) are the verified best write mode for this scatter geometry.
// Store: acc -> LDS [2][64][17] (2-way bank alias = free), one barrier, then
// 2 NT f32x4 stores per thread (4 planes x 256B contiguous per wave per group).

__global__ __launch_bounds__(256) void gather_ell(const float* __restrict__ inP,
                                                  const int* __restrict__ deg,
                                                  const unsigned short* __restrict__ ell16,
                                                  float* __restrict__ out) {
    __shared__ float lds[2][NODEB][17];
    int b     = blockIdx.x;                     // [0, (NGRP/2)*NBLK)
    int k     = b & 7;                          // XCD slot
    int r     = b >> 3;
    int nb    = r % NBLK;
    int pp    = r / NBLK;                       // pair-phase 0..3
    int gA    = pp * 16 + k;
    int gB    = gA + 8;
    int tid   = threadIdx.x;
    int s     = tid >> 2;                       // node-local 0..63
    int q     = tid & 3;                        // plane quad 0..3
    int n     = nb * NODEB + s;

    float4 aA = make_float4(0.f, 0.f, 0.f, 0.f);
    float4 aB = make_float4(0.f, 0.f, 0.f, 0.f);
    if (n < NODES) {
        int d = deg[n];
        const u32x4 e = *reinterpret_cast<const u32x4*>(ell16 + (size_t)n * ELLW);
        unsigned cs[8] = { e.x & 0xFFFFu, e.x >> 16, e.y & 0xFFFFu, e.y >> 16,
                           e.z & 0xFFFFu, e.z >> 16, e.w & 0xFFFFu, e.w >> 16 };
        const float* __restrict__ baseA = inP + (size_t)gA * NCLIQ * 16 + q * 4;
        const float* __restrict__ baseB = inP + (size_t)gB * NCLIQ * 16 + q * 4;
        #pragma unroll
        for (int i = 0; i < 8; ++i) {
            if (i < d) {
                size_t off = (size_t)cs[i] * 16;
                const float4 pA = *reinterpret_cast<const float4*>(baseA + off);
                const float4 pB = *reinterpret_cast<const float4*>(baseB + off);
                aA.x += pA.x; aA.y += pA.y; aA.z += pA.z; aA.w += pA.w;
                aB.x += pB.x; aB.y += pB.y; aB.z += pB.z; aB.w += pB.w;
            }
        }
        if (d > 8) {                            // P(deg>8) ~ 0.02%/node: scalar tail
            for (int i = 8; i < d && i < ELLW; ++i) {
                size_t off = (size_t)ell16[(size_t)n * ELLW + i] * 16;
                const float4 pA = *reinterpret_cast<const float4*>(baseA + off);
                const float4 pB = *reinterpret_cast<const float4*>(baseB + off);
                aA.x += pA.x; aA.y += pA.y; aA.z += pA.z; aA.w += pA.w;
                aB.x += pB.x; aB.y += pB.y; aB.z += pB.z; aB.w += pB.w;
            }
        }
    }
    lds[0][s][q * 4 + 0] = aA.x;  lds[0][s][q * 4 + 1] = aA.y;
    lds[0][s][q * 4 + 2] = aA.z;  lds[0][s][q * 4 + 3] = aA.w;
    lds[1][s][q * 4 + 0] = aB.x;  lds[1][s][q * 4 + 1] = aB.y;
    lds[1][s][q * 4 + 2] = aB.z;  lds[1][s][q * 4 + 3] = aB.w;
    __syncthreads();

    int p  = tid >> 4;                          // plane 0..15
    int i4 = (tid & 15) * 4;                    // node chunk base
    int n0 = nb * NODEB + i4;
    if (n0 + 3 < NODES) {                       // NODES%4==0: no partial vec4
        f32x4 oA = { lds[0][i4][p], lds[0][i4 + 1][p], lds[0][i4 + 2][p], lds[0][i4 + 3][p] };
        f32x4 oB = { lds[1][i4][p], lds[1][i4 + 1][p], lds[1][i4 + 2][p], lds[1][i4 + 3][p] };
        __builtin_nontemporal_store(oA,
            reinterpret_cast<f32x4*>(out + (size_t)(gA * 16 + p) * NODES + n0));
        __builtin_nontemporal_store(oB,
            reinterpret_cast<f32x4*>(out + (size_t)(gB * 16 + p) * NODES + n0));
    }
}

// ---------------- launch ----------------

extern "C" void kernel_launch(void* const* d_in, const int* in_sizes, int n_in,
                              void* d_out, int out_size, void* d_ws, size_t ws_size,
                              hipStream_t stream) {
    const float* in         = (const float*)d_in[0];
    const int*   node_ids   = (const int*)d_in[1];
    const int*   clique_ids = (const int*)d_in[2];
    float*       out        = (float*)d_out;

    // ws layout: counts[50000] int | ell16[50000*16] ushort | inP[64*12500*16] float
    int*            counts = (int*)d_ws;
    unsigned short* ell16  = (unsigned short*)(counts + NODES);          // byte 200,000
    float*          inP    = (float*)((char*)d_ws + 200000 + 1600000);   // byte 1,800,000 (16B-aligned)

    zero_counts<<<(NODES / 4 + 255) / 256, 256, 0, stream>>>((int4*)counts);
    fill_pack<<<FILL_BLOCKS + PACK_BLOCKS, 256, 0, stream>>>(node_ids, clique_ids,
                                                             counts, ell16, in, inP);
    gather_ell<<<(NGRP / 2) * NBLK, 256, 0, stream>>>(inP, counts, ell16, out);
}